// Round 4
// baseline (239.131 us; speedup 1.0000x reference)
//
#include <hip/hip_runtime.h>
#include <hip/hip_bf16.h>
#include <cstddef>

// Problem constants (from reference)
#define QN 10000
#define DD 64
#define MM 50
#define BB 64
#define TT 512
#define WPAD 52    // padded w row stride in floats (208 B, 16B-aligned rows)
#define CC 32      // chunks (compile-time -> full unroll)
#define LL 16      // steps per chunk = TT/CC
#define MH 25      // m's per half-wave split in kA/kC

__device__ __forceinline__ float rl(float v, int l) {
  return __uint_as_float(__builtin_amdgcn_readlane(__float_as_uint(v), l));
}
__device__ __forceinline__ float sigf(float x) {
  return 1.f / (1.f + __expf(-x));
}
__device__ __forceinline__ float tanhf_fast(float x) {
  const float t2 = __expf(2.f * x);
  return 1.f - 2.f / (t2 + 1.f);
}

// ---------------------------------------------------------------------------
// k1: GEMV layout (lane = row). 3 paths by block range, 128 blocks each:
//   path 0: w = softmax(k @ Mk^T)   (Mk^T staged in LDS, 52-padded rows)
//   path 1: e = sigmoid(v @ e_W + e_b)
//   path 2: a = tanh(v @ a_W + a_b)
// Weights broadcast from LDS (same-address ds_read_b128 = conflict-free);
// row data gathered per-lane into VGPRs; zero cross-lane ops.
// ---------------------------------------------------------------------------
__global__ __launch_bounds__(256, 1) void k1_gemv(
    const int* __restrict__ question, const int* __restrict__ response,
    const float* __restrict__ k_emb, const float* __restrict__ v_emb,
    const float* __restrict__ Mk,
    const float* __restrict__ e_W, const float* __restrict__ e_b,
    const float* __restrict__ a_W, const float* __restrict__ a_b,
    float* __restrict__ w_buf, float* __restrict__ e_buf, float* __restrict__ a_buf) {
  __shared__ float lds[4160];
  const int tid = (int)threadIdx.x;
  const int lane = tid & 63;
  const int wslot = __builtin_amdgcn_readfirstlane(tid >> 6);
  const int path = blockIdx.x >> 7;          // 0=w, 1=e, 2=a
  const int blk = blockIdx.x & 127;
  const int gid = blk * 4 + wslot;           // 0..511
  const int row = gid * 64 + lane;           // 0..32767

  if (path == 0) {
    // ---- issue row gathers early (independent of LDS staging) ----
    const int q = question[row];
    const float* __restrict__ krow = k_emb + (size_t)q * 64;
    float x[64];
#pragma unroll
    for (int i = 0; i < 64; i += 4) {
      const float4 t = *(const float4*)(krow + i);
      x[i] = t.x; x[i + 1] = t.y; x[i + 2] = t.z; x[i + 3] = t.w;
    }
    // ---- stage Mk^T into LDS: lds[i*52 + m] = Mk[m][i]; pad m=50,51 = 0 ----
    for (int idx = tid; idx < 3328; idx += 256) lds[idx] = 0.f;
    __syncthreads();
    for (int idx = tid; idx < 3200; idx += 256) {
      const int m = idx >> 6, i = idx & 63;
      lds[i * 52 + m] = Mk[idx];
    }
    __syncthreads();

    float l[52];
#pragma unroll
    for (int m = 0; m < 52; ++m) l[m] = 0.f;
#pragma unroll 2
    for (int i = 0; i < 64; ++i) {
      float w[52];
#pragma unroll
      for (int j = 0; j < 52; j += 4) {
        const float4 t = *(const float4*)(&lds[i * 52 + j]);  // broadcast
        w[j] = t.x; w[j + 1] = t.y; w[j + 2] = t.z; w[j + 3] = t.w;
      }
#pragma unroll
      for (int m = 0; m < 50; ++m) l[m] = fmaf(x[i], w[m], l[m]);
    }
    // per-lane softmax over l[0..49]
    float mx = l[0];
#pragma unroll
    for (int m = 1; m < 50; ++m) mx = fmaxf(mx, l[m]);
    float s = 0.f;
#pragma unroll
    for (int m = 0; m < 50; ++m) { l[m] = __expf(l[m] - mx); s += l[m]; }
    const float inv = 1.f / s;
#pragma unroll
    for (int m = 0; m < 50; ++m) l[m] *= inv;
    l[50] = 0.f; l[51] = 0.f;
    float* __restrict__ wo = w_buf + (size_t)row * WPAD;
#pragma unroll
    for (int m = 0; m < 52; m += 4) {
      float4 o; o.x = l[m]; o.y = l[m + 1]; o.z = l[m + 2]; o.w = l[m + 3];
      *(float4*)(wo + m) = o;
    }
  } else {
    // ---- e or a path ----
    const int q = question[row];
    const int r = response[row];
    const float* __restrict__ vrow = v_emb + ((size_t)q + (size_t)QN * r) * 64;
    float x[64];
#pragma unroll
    for (int i = 0; i < 64; i += 4) {
      const float4 t = *(const float4*)(vrow + i);
      x[i] = t.x; x[i + 1] = t.y; x[i + 2] = t.z; x[i + 3] = t.w;
    }
    const float* __restrict__ W = (path == 1) ? e_W : a_W;
    const float* __restrict__ Bv = (path == 1) ? e_b : a_b;
    for (int idx = tid; idx < 4096; idx += 256) lds[idx] = W[idx];
    if (tid < 64) lds[4096 + tid] = Bv[tid];
    __syncthreads();

    float acc[64];
#pragma unroll
    for (int d = 0; d < 64; ++d) acc[d] = 0.f;
#pragma unroll 2
    for (int i = 0; i < 64; ++i) {
      float w[64];
#pragma unroll
      for (int j = 0; j < 64; j += 4) {
        const float4 t = *(const float4*)(&lds[i * 64 + j]);  // broadcast
        w[j] = t.x; w[j + 1] = t.y; w[j + 2] = t.z; w[j + 3] = t.w;
      }
#pragma unroll
      for (int d = 0; d < 64; ++d) acc[d] = fmaf(x[i], w[d], acc[d]);
    }
    float* __restrict__ o = ((path == 1) ? e_buf : a_buf) + (size_t)row * 64;
    if (path == 1) {
#pragma unroll
      for (int d = 0; d < 64; d += 4) {
        float4 ov;
        ov.x = sigf(acc[d] + lds[4096 + d]);
        ov.y = sigf(acc[d + 1] + lds[4096 + d + 1]);
        ov.z = sigf(acc[d + 2] + lds[4096 + d + 2]);
        ov.w = sigf(acc[d + 3] + lds[4096 + d + 3]);
        *(float4*)(o + d) = ov;
      }
    } else {
#pragma unroll
      for (int d = 0; d < 64; d += 4) {
        float4 ov;
        ov.x = tanhf_fast(acc[d] + lds[4096 + d]);
        ov.y = tanhf_fast(acc[d + 1] + lds[4096 + d + 1]);
        ov.z = tanhf_fast(acc[d + 2] + lds[4096 + d + 2]);
        ov.w = tanhf_fast(acc[d + 3] + lds[4096 + d + 3]);
        *(float4*)(o + d) = ov;
      }
    }
  }
}

// ---------------------------------------------------------------------------
// kA: composed affine (A,B) per (m,d) for each (b,chunk). Two waves per unit
// (25 m's each); lane = d; fully unrolled LL=16 steps; w broadcast via
// coalesced lane load + v_readlane. No barriers, no LDS.  (unchanged)
// ---------------------------------------------------------------------------
__global__ __launch_bounds__(256) void kA_chunk(
    const float* __restrict__ w_buf, const float* __restrict__ e_buf,
    const float* __restrict__ a_buf, const float* __restrict__ mask,
    float* __restrict__ A_arr, float* __restrict__ B_arr) {
  const int lane = threadIdx.x & 63;
  const int wslot = __builtin_amdgcn_readfirstlane((int)(threadIdx.x >> 6));
  const int gid = blockIdx.x * 4 + wslot;              // 0..4095
  const int unit = gid >> 1;                           // b*CC + c
  const int m0 = (gid & 1) * MH;
  const int b = unit >> 5;                             // CC = 32
  const int c = unit & 31;

  float Am[MH], Bm[MH];
#pragma unroll
  for (int m = 0; m < MH; ++m) { Am[m] = 1.f; Bm[m] = 0.f; }

  const size_t row0 = (size_t)b * TT + c * LL;
#pragma unroll
  for (int j = 0; j < LL; ++j) {
    const size_t row = row0 + j;
    const float wv = w_buf[row * WPAD + lane];         // coalesced lane load
    const float ed = e_buf[row * 64 + lane];
    const float ad = a_buf[row * 64 + lane];
    const float mv = mask[row];
    if (mv == 1.0f) {
#pragma unroll
      for (int m = 0; m < MH; ++m) {
        const float wm = rl(wv, m0 + m);               // wave-uniform scalar
        const float al = fmaf(-wm, ed, 1.0f);
        Am[m] *= al;
        Bm[m] = fmaf(Bm[m], al, wm * ad);
      }
    }
  }
  float* __restrict__ Ad = A_arr + (size_t)unit * (MM * 64);
  float* __restrict__ Bd = B_arr + (size_t)unit * (MM * 64);
#pragma unroll
  for (int m = 0; m < MH; ++m) {
    Ad[(m0 + m) * 64 + lane] = Am[m];
    Bd[(m0 + m) * 64 + lane] = Bm[m];
  }
}

// ---------------------------------------------------------------------------
// kB: chunk-entry states. Parallel over B*M*D = 204,800 elements. (unchanged)
// ---------------------------------------------------------------------------
__global__ __launch_bounds__(256) void kB_entry(
    const float* __restrict__ A_arr, const float* __restrict__ B_arr,
    const float* __restrict__ Mv0, float* __restrict__ entry) {
  const int idx = blockIdx.x * 256 + (int)threadIdx.x; // < 204800
  const int b = idx / (MM * 64);
  const int r = idx - b * (MM * 64);
  const size_t base = (size_t)b * CC * (MM * 64) + r;

  float Ac[CC], Bc[CC];
#pragma unroll
  for (int c = 0; c < CC; ++c) {
    Ac[c] = A_arr[base + (size_t)c * (MM * 64)];
    Bc[c] = B_arr[base + (size_t)c * (MM * 64)];
  }
  float s = Mv0[r];
#pragma unroll
  for (int c = 0; c < CC; ++c) {
    entry[base + (size_t)c * (MM * 64)] = s;
    s = fmaf(Ac[c], s, Bc[c]);
  }
}

// ---------------------------------------------------------------------------
// kC: replay each chunk from its entry state, emitting partial reads.
// Two waves per unit; fully unrolled; no barriers.  (unchanged)
// ---------------------------------------------------------------------------
__global__ __launch_bounds__(256) void kC_read(
    const float* __restrict__ w_buf, const float* __restrict__ e_buf,
    const float* __restrict__ a_buf, const float* __restrict__ mask,
    const float* __restrict__ entry, float* __restrict__ read_part,
    size_t rN) {
  const int lane = threadIdx.x & 63;
  const int wslot = __builtin_amdgcn_readfirstlane((int)(threadIdx.x >> 6));
  const int gid = blockIdx.x * 4 + wslot;              // 0..4095
  const int unit = gid >> 1;                           // b*CC + c
  const int half = gid & 1;
  const int m0 = half * MH;
  const int b = unit >> 5;
  const int c = unit & 31;

  float s[MH];
  const float* __restrict__ ep = entry + (size_t)unit * (MM * 64);
#pragma unroll
  for (int m = 0; m < MH; ++m) s[m] = ep[(m0 + m) * 64 + lane];

  float* __restrict__ rp = read_part + half * rN;
#pragma unroll
  for (int j = 0; j < LL; ++j) {
    const int t = c * LL + j;
    const size_t row = (size_t)b * TT + t;
    const float wv = w_buf[row * WPAD + lane];
    const float ed = e_buf[row * 64 + lane];
    const float ad = a_buf[row * 64 + lane];
    const float mv = mask[row];

    if (t >= 1) {                                      // uniform branch
      float a0 = 0.f, a1 = 0.f;
#pragma unroll
      for (int m = 0; m < MH; m += 2) {
        a0 = fmaf(rl(wv, m0 + m), s[m], a0);
        if (m + 1 < MH) a1 = fmaf(rl(wv, m0 + m + 1), s[m + 1], a1);
      }
      rp[((size_t)b * (TT - 1) + (t - 1)) * 64 + lane] = a0 + a1;
    }
    if (mv == 1.0f) {
#pragma unroll
      for (int m = 0; m < MH; ++m) {
        const float wm = rl(wv, m0 + m);
        s[m] = fmaf(wm, fmaf(-s[m], ed, ad), s[m]);
      }
    }
  }
}

// ---------------------------------------------------------------------------
// k3: GEMV layout (lane = row). f = tanh([read | k_{t+1}] @ f_W + f_b);
// p = f @ p_W + p_b. f_W (32 KB) staged in LDS, broadcast reads; x and f[64]
// in VGPRs; coalesced 1-float output store; no cross-lane ops.
// ---------------------------------------------------------------------------
__global__ __launch_bounds__(256, 1) void k3_gemv(
    const int* __restrict__ question, const float* __restrict__ k_emb,
    const float* __restrict__ read_part, size_t rN,
    const float* __restrict__ f_W, const float* __restrict__ f_b,
    const float* __restrict__ p_W, const float* __restrict__ p_b,
    float* __restrict__ out) {
  __shared__ float lds[8192 + 128];
  const int tid = (int)threadIdx.x;
  const int lane = tid & 63;
  const int wslot = __builtin_amdgcn_readfirstlane(tid >> 6);
  const int gid = blockIdx.x * 4 + wslot;              // 0..511

  // stage f_W + f_b + p_W
  for (int idx = tid; idx < 8192; idx += 256) lds[idx] = f_W[idx];
  if (tid < 64) lds[8192 + tid] = f_b[tid];
  else if (tid < 128) lds[8192 + tid] = p_W[tid - 64];
  __syncthreads();
  if (gid >= 511) return;                              // after the barrier

  const int row = gid * 64 + lane;                     // 0..32703
  const int b = row / (TT - 1);
  const int tp = row - b * (TT - 1);
  const int qn = question[b * TT + tp + 1];

  // x = read (r0 + r1)
  const float* __restrict__ r0 = read_part + (size_t)row * 64;
  const float* __restrict__ r1 = r0 + rN;
  float x[64];
#pragma unroll
  for (int i = 0; i < 64; i += 4) {
    const float4 u = *(const float4*)(r0 + i);
    const float4 v = *(const float4*)(r1 + i);
    x[i] = u.x + v.x; x[i + 1] = u.y + v.y;
    x[i + 2] = u.z + v.z; x[i + 3] = u.w + v.w;
  }
  float f[64];
#pragma unroll
  for (int d = 0; d < 64; ++d) f[d] = 0.f;
#pragma unroll 2
  for (int i = 0; i < 64; ++i) {
    float w[64];
#pragma unroll
    for (int j = 0; j < 64; j += 4) {
      const float4 t = *(const float4*)(&lds[i * 64 + j]);   // broadcast
      w[j] = t.x; w[j + 1] = t.y; w[j + 2] = t.z; w[j + 3] = t.w;
    }
#pragma unroll
    for (int d = 0; d < 64; ++d) f[d] = fmaf(x[i], w[d], f[d]);
  }
  // x = k_{t+1}
  const float* __restrict__ krow = k_emb + (size_t)qn * 64;
#pragma unroll
  for (int i = 0; i < 64; i += 4) {
    const float4 t = *(const float4*)(krow + i);
    x[i] = t.x; x[i + 1] = t.y; x[i + 2] = t.z; x[i + 3] = t.w;
  }
#pragma unroll 2
  for (int i = 0; i < 64; ++i) {
    float w[64];
#pragma unroll
    for (int j = 0; j < 64; j += 4) {
      const float4 t = *(const float4*)(&lds[(64 + i) * 64 + j]); // broadcast
      w[j] = t.x; w[j + 1] = t.y; w[j + 2] = t.z; w[j + 3] = t.w;
    }
#pragma unroll
    for (int d = 0; d < 64; ++d) f[d] = fmaf(x[i], w[d], f[d]);
  }
  // epilogue: tanh, dot with p_W
  float p = 0.f;
#pragma unroll
  for (int d = 0; d < 64; ++d) {
    const float fv = tanhf_fast(f[d] + lds[8192 + d]);
    p = fmaf(fv, lds[8256 + d], p);
  }
  out[row] = p + p_b[0];
}

// ---------------------------------------------------------------------------
extern "C" void kernel_launch(void* const* d_in, const int* in_sizes, int n_in,
                              void* d_out, int out_size, void* d_ws, size_t ws_size,
                              hipStream_t stream) {
  const int*   question = (const int*)d_in[0];
  const int*   response = (const int*)d_in[1];
  const float* mask     = (const float*)d_in[2];
  const float* k_emb    = (const float*)d_in[3];
  const float* v_emb    = (const float*)d_in[4];
  const float* Mk       = (const float*)d_in[5];
  const float* Mv0      = (const float*)d_in[6];
  const float* e_W      = (const float*)d_in[7];
  const float* e_b      = (const float*)d_in[8];
  const float* a_W      = (const float*)d_in[9];
  const float* a_b      = (const float*)d_in[10];
  const float* f_W      = (const float*)d_in[11];
  const float* f_b      = (const float*)d_in[12];
  const float* p_W      = (const float*)d_in[13];
  const float* p_b      = (const float*)d_in[14];
  float* out = (float*)d_out;

  // workspace layout (floats)
  const size_t wN = (size_t)BB * TT * WPAD;       // 1,703,936
  const size_t eN = (size_t)BB * TT * 64;         // 2,097,152
  const size_t rN = (size_t)BB * (TT - 1) * 64;   // 2,093,056
  const size_t abN = (size_t)BB * CC * MM * 64;   // 6,553,600
  float* ws = (float*)d_ws;
  float* w_buf     = ws;
  float* e_buf     = w_buf + wN;
  float* a_buf     = e_buf + eN;
  float* read_part = a_buf + eN;                  // 2 * rN
  float* A_arr     = read_part + 2 * rN;
  float* B_arr     = A_arr + abN;
  float* entry     = B_arr + abN;
  // total = 29,745,152 floats = 119 MB (< ws_size)

  hipLaunchKernelGGL(k1_gemv, dim3(384), dim3(256), 0, stream,
                     question, response, k_emb, v_emb, Mk, e_W, e_b, a_W, a_b,
                     w_buf, e_buf, a_buf);
  hipLaunchKernelGGL(kA_chunk, dim3(1024), dim3(256), 0, stream,
                     w_buf, e_buf, a_buf, mask, A_arr, B_arr);
  hipLaunchKernelGGL(kB_entry, dim3((BB * MM * 64) / 256), dim3(256), 0, stream,
                     A_arr, B_arr, Mv0, entry);
  hipLaunchKernelGGL(kC_read, dim3(1024), dim3(256), 0, stream,
                     w_buf, e_buf, a_buf, mask, entry, read_part, rN);
  hipLaunchKernelGGL(k3_gemv, dim3(128), dim3(256), 0, stream,
                     question, k_emb, read_part, rN, f_W, f_b, p_W, p_b, out);
}